// Round 13
// baseline (224.923 us; speedup 1.0000x reference)
//
#include <hip/hip_runtime.h>
#include <math.h>

// ---------------------------------------------------------------------------
// TersoffAttention (R12 = R11 + padded counters + nt bucket stores).
//   R11: fused_b 84us, but init+scatter ~135us. Theory: 25 counters share
//   each 64B line -> ~250 serialized memory-side RMWs per line. Pad cnt to
//   one counter per 64B line (PSTRIDE=16 ints); bucket writes become
//   nontemporal. fused_b math identical to R11 (passed, absmax 0.0156).
// Chain: init -> scatter -> fused.  R10 CSR chain kept as ws-too-small
// fallback (never taken at these sizes).
// ---------------------------------------------------------------------------

#define LOG2E 1.4426950408889634f
#define SCAN_B 256
#define SPILL_PAIRS 65536

// ===================== bucket path =====================

__global__ void ta_init_b(const float* __restrict__ r,
                          float4* __restrict__ rnorm4,
                          int* __restrict__ cnt,       // E*PS ints, padded
                          int* __restrict__ spill_cnt,
                          int E, int n4) {             // n4 = E*PS/4
    int i = blockIdx.x * blockDim.x + threadIdx.x;
    if (i < n4) ((int4*)cnt)[i] = make_int4(0, 0, 0, 0);
    if (i < E) {
        float rx = r[i * 3 + 0], ry = r[i * 3 + 1], rz = r[i * 3 + 2];
        float inv = rsqrtf(rx * rx + ry * ry + rz * rz);
        rnorm4[i] = make_float4(rx * inv, ry * inv, rz * inv, 0.f);
    }
    if (i == 0) *spill_cnt = 0;
}

__global__ void ta_scatter_b(const int* __restrict__ t_dst,
                             const int* __restrict__ t_src,
                             int* __restrict__ cnt,
                             int* __restrict__ bucket,
                             int* __restrict__ spill,      // pairs (d, src)
                             int* __restrict__ spill_cnt,
                             int T, int CAP, int PS) {
    int i = blockIdx.x * blockDim.x + threadIdx.x;
    int T4 = T >> 2;
    if (i < T4) {
        int4 d = ((const int4*)t_dst)[i];
        int4 s = ((const int4*)t_src)[i];
        int p0 = atomicAdd(&cnt[(size_t)d.x * PS], 1);
        int p1 = atomicAdd(&cnt[(size_t)d.y * PS], 1);
        int p2 = atomicAdd(&cnt[(size_t)d.z * PS], 1);
        int p3 = atomicAdd(&cnt[(size_t)d.w * PS], 1);
        if (p0 < CAP) __builtin_nontemporal_store(s.x, &bucket[(size_t)d.x * CAP + p0]);
        else { int u = atomicAdd(spill_cnt, 1); if (u < SPILL_PAIRS) { spill[2*u] = d.x; spill[2*u+1] = s.x; } }
        if (p1 < CAP) __builtin_nontemporal_store(s.y, &bucket[(size_t)d.y * CAP + p1]);
        else { int u = atomicAdd(spill_cnt, 1); if (u < SPILL_PAIRS) { spill[2*u] = d.y; spill[2*u+1] = s.y; } }
        if (p2 < CAP) __builtin_nontemporal_store(s.z, &bucket[(size_t)d.z * CAP + p2]);
        else { int u = atomicAdd(spill_cnt, 1); if (u < SPILL_PAIRS) { spill[2*u] = d.z; spill[2*u+1] = s.z; } }
        if (p3 < CAP) __builtin_nontemporal_store(s.w, &bucket[(size_t)d.w * CAP + p3]);
        else { int u = atomicAdd(spill_cnt, 1); if (u < SPILL_PAIRS) { spill[2*u] = d.w; spill[2*u+1] = s.w; } }
    }
    if (i == 0) {                       // generic tail (T%4 != 0)
        for (int t = T4 << 2; t < T; ++t) {
            int d = t_dst[t];
            int p = atomicAdd(&cnt[(size_t)d * PS], 1);
            if (p < CAP) bucket[(size_t)d * CAP + p] = t_src[t];
            else { int u = atomicAdd(spill_cnt, 1); if (u < SPILL_PAIRS) { spill[2*u] = d; spill[2*u+1] = t_src[t]; } }
        }
    }
}

// fused: one wave per dst edge e. Phase A (lane=triplet): acos batch.
// Phase B: 8 groups x 8 lanes, 8 triplets/pass, 8 channels/lane.
__global__ void ta_fused_b(const float* __restrict__ xij,
                           const float* __restrict__ attn,
                           const float4* __restrict__ rnorm4,
                           const int* __restrict__ bucket,
                           const int* __restrict__ cnt,
                           const int* __restrict__ spill,
                           const int* __restrict__ spill_cnt,
                           float* __restrict__ ft, int E, int CAP, int PS) {
    const int lane = threadIdx.x & 63;
    const int waveId = blockIdx.x * (blockDim.x >> 6) + (threadIdx.x >> 6);
    if (waveId >= E) return;
    const int e = waveId;
    const int g   = lane >> 3;          // group (triplet slot within pass)
    const int sub = lane & 7;           // lane within group
    const int c0  = sub * 8;            // first channel of this lane's octet
    const float fc0 = (float)c0;

    int len = cnt[(size_t)e * PS];
    int eff = (len < CAP) ? len : CAP;  // in-bucket count
    const int* bkt = bucket + (size_t)e * CAP;

    float xd[8], at[8];
    const float* xdp = xij + (size_t)e * 64 + c0;
    *(float4*)&xd[0] = *(const float4*)(xdp);
    *(float4*)&xd[4] = *(const float4*)(xdp + 4);
    *(float4*)&at[0] = *(const float4*)(attn + c0);
    *(float4*)&at[4] = *(const float4*)(attn + c0 + 4);
    const float4 rd = rnorm4[e];

    float m = -3.402823466e38f, den = 0.f;
    float acc[8] = {0, 0, 0, 0, 0, 0, 0, 0};

    for (int chunk = 0; chunk < eff; chunk += 64) {
        int cl = eff - chunk; if (cl > 64) cl = 64;
        // ---- phase A: lane = triplet slot ----
        int idx = chunk + lane; if (idx >= eff) idx = eff - 1;
        int sv = bkt[idx];
        float4 rs = rnorm4[sv];
        float cosj = rs.x * rd.x + rs.y * rd.y + rs.z * rd.z;
        cosj = fminf(fmaxf(cosj, -1.0f + 1e-6f), 1.0f - 1e-6f);
        float th2p = acosf(cosj) * 0.15915493667125702f;   // theta/(2pi)

        // ---- phase B: 8 triplets per pass (group g takes triplet j8+g) ----
        for (int j8 = 0; j8 < cl; j8 += 8) {
            int jj = j8 + g;
            bool active = (jj < cl);
            int jc = active ? jj : 0;
            float th = __shfl(th2p, jc, 64);
            float tc = __shfl(cosj, jc, 64);   // cos(theta): Chebyshev mult/2
            int   s  = __shfl(sv,   jc, 64);

            const float* xsp = xij + (size_t)s * 64 + c0;
            float xs[8];
            *(float4*)&xs[0] = *(const float4*)(xsp);
            *(float4*)&xs[4] = *(const float4*)(xsp + 4);

            float r0 = th * fc0;
            float z0 = __builtin_amdgcn_cosf(r0 - floorf(r0));
            float r1 = r0 + th;
            float z1 = __builtin_amdgcn_cosf(r1 - floorf(r1));
            float twoc = 2.0f * tc;

            float part = 0.f;
            float zkm1 = z0, zk = z1;
            #pragma unroll
            for (int k = 0; k < 8; ++k) {
                float z = (k == 0) ? z0 : zk;
                float v = z + xs[k] + xd[k];
                float ez = __builtin_amdgcn_exp2f(-v * LOG2E);
                float sl = v * __builtin_amdgcn_rcpf(1.0f + ez);   // silu
                part = fmaf(sl, at[k], part);
                if (k > 0) {
                    float zn = fmaf(twoc, zk, -zkm1);
                    zkm1 = zk; zk = zn;
                }
            }
            part += __shfl_xor(part, 1, 64);
            part += __shfl_xor(part, 2, 64);
            part += __shfl_xor(part, 4, 64);
            float contrib = active ? part : -3.402823466e38f;
            float mn = fmaxf(m, contrib);
            float scale = __builtin_amdgcn_exp2f((m - mn) * LOG2E);
            float p     = __builtin_amdgcn_exp2f((contrib - mn) * LOG2E);
            den = den * scale + p;
            #pragma unroll
            for (int k = 0; k < 8; ++k) acc[k] = fmaf(p, xs[k], acc[k] * scale);
            m = mn;
        }
    }

    // overflow slow path (never taken for CAP=32 on this data)
    if (len > CAP) {
        int ns = *spill_cnt; if (ns > SPILL_PAIRS) ns = SPILL_PAIRS;
        for (int u = 0; u < ns; ++u) {
            int d2 = spill[2 * u];
            if (d2 != e) continue;
            int s2 = spill[2 * u + 1];
            float4 rs = rnorm4[s2];
            float cosj = rs.x * rd.x + rs.y * rd.y + rs.z * rd.z;
            cosj = fminf(fmaxf(cosj, -1.0f + 1e-6f), 1.0f - 1e-6f);
            float th = acosf(cosj) * 0.15915493667125702f;
            const float* xsp = xij + (size_t)s2 * 64 + c0;
            float xs[8];
            *(float4*)&xs[0] = *(const float4*)(xsp);
            *(float4*)&xs[4] = *(const float4*)(xsp + 4);
            float r0 = th * fc0;
            float z0 = __builtin_amdgcn_cosf(r0 - floorf(r0));
            float r1 = r0 + th;
            float z1 = __builtin_amdgcn_cosf(r1 - floorf(r1));
            float twoc = 2.0f * cosj;
            float part = 0.f;
            float zkm1 = z0, zk = z1;
            #pragma unroll
            for (int k = 0; k < 8; ++k) {
                float z = (k == 0) ? z0 : zk;
                float v = z + xs[k] + xd[k];
                float ez = __builtin_amdgcn_exp2f(-v * LOG2E);
                float sl = v * __builtin_amdgcn_rcpf(1.0f + ez);
                part = fmaf(sl, at[k], part);
                if (k > 0) { float zn = fmaf(twoc, zk, -zkm1); zkm1 = zk; zk = zn; }
            }
            part += __shfl_xor(part, 1, 64);
            part += __shfl_xor(part, 2, 64);
            part += __shfl_xor(part, 4, 64);
            if (g == 0) {
                float mn = fmaxf(m, part);
                float scale = __builtin_amdgcn_exp2f((m - mn) * LOG2E);
                float p     = __builtin_amdgcn_exp2f((part - mn) * LOG2E);
                den = den * scale + p;
                #pragma unroll
                for (int k = 0; k < 8; ++k) acc[k] = fmaf(p, xs[k], acc[k] * scale);
                m = mn;
            }
        }
    }

    if (len > 1) {                             // merge the 8 groups
        #pragma unroll
        for (int off = 8; off < 64; off <<= 1) {
            float m2 = __shfl_xor(m, off, 64);
            float d2 = __shfl_xor(den, off, 64);
            float mn = fmaxf(m, m2);
            float s1 = __builtin_amdgcn_exp2f((m - mn) * LOG2E);
            float s2 = __builtin_amdgcn_exp2f((m2 - mn) * LOG2E);
            den = den * s1 + d2 * s2;
            #pragma unroll
            for (int k = 0; k < 8; ++k) {
                float a2 = __shfl_xor(acc[k], off, 64);
                acc[k] = acc[k] * s1 + a2 * s2;
            }
            m = mn;
        }
    }

    float rden = (len > 0) ? __builtin_amdgcn_rcpf(den) : 0.f;
    if (lane < 8) {
        float out[8];
        #pragma unroll
        for (int k = 0; k < 8; ++k) out[k] = acc[k] * rden;
        float* fo = ft + (size_t)e * 64 + lane * 8;
        *(float4*)(fo)     = *(float4*)&out[0];
        *(float4*)(fo + 4) = *(float4*)&out[4];
    }
}

// ===================== R10 fallback path (proven, ws-too-small only) ========

__global__ void ta_init(const float* __restrict__ r, float4* __restrict__ rnorm4,
                        int* __restrict__ rowptr, int E) {
    int i = blockIdx.x * blockDim.x + threadIdx.x;
    if (i < E) {
        float rx = r[i * 3 + 0], ry = r[i * 3 + 1], rz = r[i * 3 + 2];
        float inv = rsqrtf(rx * rx + ry * ry + rz * rz);
        rnorm4[i] = make_float4(rx * inv, ry * inv, rz * inv, 0.f);
        rowptr[i] = 0;
    }
}

__global__ void ta_hist(const int* __restrict__ t_dst, int* __restrict__ rowptr, int T) {
    int i = blockIdx.x * blockDim.x + threadIdx.x;
    int T4 = T >> 2;
    if (i < T4) {
        int4 d = ((const int4*)t_dst)[i];
        atomicAdd(&rowptr[d.x], 1);
        atomicAdd(&rowptr[d.y], 1);
        atomicAdd(&rowptr[d.z], 1);
        atomicAdd(&rowptr[d.w], 1);
    }
    if (i == 0) for (int u = T4 << 2; u < T; ++u) atomicAdd(&rowptr[t_dst[u]], 1);
}

__global__ void ta_scan1(int* __restrict__ rowptr, int* __restrict__ bsum, int E) {
    __shared__ int sm[SCAN_B];
    int i = blockIdx.x * SCAN_B + threadIdx.x;
    int v = (i < E) ? rowptr[i] : 0;
    sm[threadIdx.x] = v;
    __syncthreads();
    int x = v;
    for (int o = 1; o < SCAN_B; o <<= 1) {
        int y = (threadIdx.x >= (unsigned)o) ? sm[threadIdx.x - o] : 0;
        __syncthreads();
        x += y; sm[threadIdx.x] = x;
        __syncthreads();
    }
    if (i < E) rowptr[i] = x - v;
    if (threadIdx.x == SCAN_B - 1) bsum[blockIdx.x] = x;
}

__global__ void ta_scan2(int* __restrict__ bsum, int n) {
    __shared__ int sm[512];
    int tid = threadIdx.x;
    int v = (tid < n) ? bsum[tid] : 0;
    sm[tid] = v;
    __syncthreads();
    int x = v;
    for (int o = 1; o < 512; o <<= 1) {
        int y = (tid >= o) ? sm[tid - o] : 0;
        __syncthreads();
        x += y; sm[tid] = x;
        __syncthreads();
    }
    if (tid < n) bsum[tid] = x - v;
}

__global__ void ta_scatter(const int* __restrict__ t_dst, const int* __restrict__ t_src,
                           int* __restrict__ rowptr, const int* __restrict__ bsum,
                           int* __restrict__ ssorted, int T) {
    int t = blockIdx.x * blockDim.x + threadIdx.x;
    if (t < T) {
        int d = t_dst[t];
        int pos = atomicAdd(&rowptr[d], 1) + bsum[d >> 8];
        ssorted[pos] = t_src[t];
    }
}

__global__ void ta_fused(const float* __restrict__ xij, const float* __restrict__ attn,
                         const float4* __restrict__ rnorm4, const int* __restrict__ ssorted,
                         const int* __restrict__ segend, const int* __restrict__ bsum,
                         float* __restrict__ ft, int E) {
    const int lane = threadIdx.x & 63;
    const int waveId = blockIdx.x * (blockDim.x >> 6) + (threadIdx.x >> 6);
    if (waveId >= E) return;
    const int e = waveId;
    const int g = lane >> 3, sub = lane & 7, c0 = sub * 8;
    const float fc0 = (float)c0;
    int end = segend[e] + bsum[e >> 8];
    int start = (e == 0) ? 0 : (segend[e - 1] + bsum[(e - 1) >> 8]);
    int len = end - start;
    float xd[8], at[8];
    const float* xdp = xij + (size_t)e * 64 + c0;
    *(float4*)&xd[0] = *(const float4*)(xdp);
    *(float4*)&xd[4] = *(const float4*)(xdp + 4);
    *(float4*)&at[0] = *(const float4*)(attn + c0);
    *(float4*)&at[4] = *(const float4*)(attn + c0 + 4);
    const float4 rd = rnorm4[e];
    float m = -3.402823466e38f, den = 0.f;
    float acc[8] = {0, 0, 0, 0, 0, 0, 0, 0};
    for (int chunk = start; chunk < end; chunk += 64) {
        int cl = end - chunk; if (cl > 64) cl = 64;
        int idx = chunk + lane; if (idx >= end) idx = end - 1;
        int sv = ssorted[idx];
        float4 rs = rnorm4[sv];
        float cosj = rs.x * rd.x + rs.y * rd.y + rs.z * rd.z;
        cosj = fminf(fmaxf(cosj, -1.0f + 1e-6f), 1.0f - 1e-6f);
        float th2p = acosf(cosj) * 0.15915493667125702f;
        for (int j8 = 0; j8 < cl; j8 += 8) {
            int jj = j8 + g;
            bool active = (jj < cl);
            int jc = active ? jj : 0;
            float th = __shfl(th2p, jc, 64);
            float tc = __shfl(cosj, jc, 64);
            int   s  = __shfl(sv,   jc, 64);
            const float* xsp = xij + (size_t)s * 64 + c0;
            float xs[8];
            *(float4*)&xs[0] = *(const float4*)(xsp);
            *(float4*)&xs[4] = *(const float4*)(xsp + 4);
            float r0 = th * fc0;
            float z0 = __builtin_amdgcn_cosf(r0 - floorf(r0));
            float r1 = r0 + th;
            float z1 = __builtin_amdgcn_cosf(r1 - floorf(r1));
            float twoc = 2.0f * tc;
            float part = 0.f;
            float zkm1 = z0, zk = z1;
            #pragma unroll
            for (int k = 0; k < 8; ++k) {
                float z = (k == 0) ? z0 : zk;
                float v = z + xs[k] + xd[k];
                float ez = __builtin_amdgcn_exp2f(-v * LOG2E);
                float sl = v * __builtin_amdgcn_rcpf(1.0f + ez);
                part = fmaf(sl, at[k], part);
                if (k > 0) { float zn = fmaf(twoc, zk, -zkm1); zkm1 = zk; zk = zn; }
            }
            part += __shfl_xor(part, 1, 64);
            part += __shfl_xor(part, 2, 64);
            part += __shfl_xor(part, 4, 64);
            float contrib = active ? part : -3.402823466e38f;
            float mn = fmaxf(m, contrib);
            float scale = __builtin_amdgcn_exp2f((m - mn) * LOG2E);
            float p     = __builtin_amdgcn_exp2f((contrib - mn) * LOG2E);
            den = den * scale + p;
            #pragma unroll
            for (int k = 0; k < 8; ++k) acc[k] = fmaf(p, xs[k], acc[k] * scale);
            m = mn;
        }
    }
    if (len > 1) {
        #pragma unroll
        for (int off = 8; off < 64; off <<= 1) {
            float m2 = __shfl_xor(m, off, 64);
            float d2 = __shfl_xor(den, off, 64);
            float mn = fmaxf(m, m2);
            float s1 = __builtin_amdgcn_exp2f((m - mn) * LOG2E);
            float s2 = __builtin_amdgcn_exp2f((m2 - mn) * LOG2E);
            den = den * s1 + d2 * s2;
            #pragma unroll
            for (int k = 0; k < 8; ++k) {
                float a2 = __shfl_xor(acc[k], off, 64);
                acc[k] = acc[k] * s1 + a2 * s2;
            }
            m = mn;
        }
    }
    float rden = (len > 0) ? __builtin_amdgcn_rcpf(den) : 0.f;
    if (lane < 8) {
        float out[8];
        #pragma unroll
        for (int k = 0; k < 8; ++k) out[k] = acc[k] * rden;
        float* fo = ft + (size_t)e * 64 + lane * 8;
        *(float4*)(fo)     = *(float4*)&out[0];
        *(float4*)(fo + 4) = *(float4*)&out[4];
    }
}

// ===================== launch =====================

extern "C" void kernel_launch(void* const* d_in, const int* in_sizes, int n_in,
                              void* d_out, int out_size, void* d_ws, size_t ws_size,
                              hipStream_t stream) {
    const float* xij   = (const float*)d_in[0];
    const float* r     = (const float*)d_in[1];
    const float* attn  = (const float*)d_in[2];
    const int*   t_src = (const int*)d_in[3];
    const int*   t_dst = (const int*)d_in[4];
    float* ft = (float*)d_out;

    const int E = in_sizes[1] / 3;   // r is [E,3]
    const int T = in_sizes[3];       // t_src is [T]

    // pick (CAP, PSTRIDE) that fits ws: prefer padded counters (64B/line)
    auto need = [&](int cap, int ps) {
        return (size_t)E * 16 + (size_t)E * ps * 4 + 4 +
               (size_t)SPILL_PAIRS * 8 + (size_t)E * cap * 4;
    };
    int CAP = 0, PS = 1;
    if      (need(32, 16) <= ws_size) { CAP = 32; PS = 16; }
    else if (need(32, 4)  <= ws_size) { CAP = 32; PS = 4;  }
    else if (need(32, 1)  <= ws_size) { CAP = 32; PS = 1;  }
    else if (need(16, 1)  <= ws_size) { CAP = 16; PS = 1;  }

    char* ws = (char*)d_ws;
    if (CAP >= 16) {
        float4* rnorm4    = (float4*)ws;
        int*    cnt       = (int*)(ws + (size_t)E * 16);
        int*    spill_cnt = (int*)((char*)cnt + (size_t)E * PS * 4);
        int*    spill     = spill_cnt + 1;
        int*    bucket    = spill + (size_t)SPILL_PAIRS * 2;

        int n4 = (E * PS) >> 2;
        int nb = ((n4 > E ? n4 : E) + 255) / 256;
        ta_init_b<<<nb, 256, 0, stream>>>(r, rnorm4, cnt, spill_cnt, E, n4);
        ta_scatter_b<<<((T >> 2) + 255) / 256, 256, 0, stream>>>(
            t_dst, t_src, cnt, bucket, spill, spill_cnt, T, CAP, PS);
        ta_fused_b<<<(E + 3) / 4, 256, 0, stream>>>(
            xij, attn, rnorm4, bucket, cnt, spill, spill_cnt, ft, E, CAP, PS);
    } else {
        // R10 fallback: rnorm4 | ssorted | rowptr | bsum
        float4* rnorm4  = (float4*)ws;
        int*    ssorted = (int*)(ws + (size_t)E * 16);
        int*    rowptr  = (int*)((char*)ssorted + (size_t)T * 4);
        int*    bsum    = (int*)((char*)rowptr + (size_t)E * 4);
        const int nScanBlocks = (E + SCAN_B - 1) / SCAN_B;

        ta_init<<<(E + 255) / 256, 256, 0, stream>>>(r, rnorm4, rowptr, E);
        ta_hist<<<((T >> 2) + 255) / 256, 256, 0, stream>>>(t_dst, rowptr, T);
        ta_scan1<<<nScanBlocks, SCAN_B, 0, stream>>>(rowptr, bsum, E);
        ta_scan2<<<1, 512, 0, stream>>>(bsum, nScanBlocks);
        ta_scatter<<<(T + 255) / 256, 256, 0, stream>>>(t_dst, t_src, rowptr, bsum, ssorted, T);
        ta_fused<<<(E + 3) / 4, 256, 0, stream>>>(xij, attn, rnorm4, ssorted, rowptr, bsum, ft, E);
    }
}